// Round 10
// baseline (1056.517 us; speedup 1.0000x reference)
//
#include <hip/hip_runtime.h>
#include <cstdint>

// LSTM: B=1024, T=336, I=64, H=256, gates 4H=1024, K = I+H = 320.
// R13 = R12 with a DIAGNOSTIC-HARDENED safety valve (2^12 instead of 2^17
// retries per tile-poll; worst case ~2.5s/dispatch, so the bench must return
// pass/fail instead of a watchdog-killed container). Structure unchanged:
// barrier2 ELIMINATED — R9 partition (64 groups x 4 members, 16 batches/
// group, 64 gate-cols/member, 256 WGs = 1/CU) with remote h polled per-lane
// DIRECTLY into MFMA B-fragments (producer's packed (tag, col|col+1) dwords
// ARE the fragment dwords): no LDS scatter, no LDS re-read, no WG-wide wait
// on the slowest poll thread. One barrier/step (cross-step LDS reuse is
// ordered: no wave passes barrier1(t+1) before all waves finish phase-1(t)).
// Poll timing = R9's proven window (issue after x-tile MFMAs, check after
// own-h MFMAs; R10/R11 proved earlier snapshots race the store and lose).
// t=1 free: memset tags = 0 = t-1, zero data. Exchange device-scope sc0+sc1.

#define NGROUP  64
#define BATCH_G 16
#define T_STEPS 336
#define I_DIM   64
#define H_DIM   256
#define VSTRIDE 136   // ushorts per staged row: x(64) + own-h(64) + 8 pad
#define PAIRS   128   // h-pairs per batch row (256 cols / 2)
#define OUT_HALF 262144  // 1024*256
#define VALVE   (1 << 12)   // bounded poll: ~1.2ms worst case per tile-poll

typedef __attribute__((ext_vector_type(8))) __bf16 bf16x8;
typedef __attribute__((ext_vector_type(8))) unsigned short ushort8_t;
typedef __attribute__((ext_vector_type(4))) float f32x4;
typedef __attribute__((ext_vector_type(4))) unsigned uint32x4;
typedef __attribute__((ext_vector_type(2))) unsigned uint32x2;

__device__ inline unsigned short f2bf(float f) {
  unsigned u = __builtin_bit_cast(unsigned, f);
  return (unsigned short)((u + 0x7fffu + ((u >> 16) & 1u)) >> 16);
}
__device__ inline float sigf(float x) { return 1.f / (1.f + __expf(-x)); }
__device__ inline float tanhfast(float x) { return 1.f - 2.f / (1.f + __expf(2.f * x)); }

// slot s (0..9) -> k-tile index kt (0..9). Slots 0,1 = x tiles; 2,3 = own h
// tiles (kt = 2+2*mid, 3+2*mid); 4..9 = the 6 remote h tiles in kt order.
__device__ inline int slot_kt(int s, int mid) {
  return (s < 2) ? s
       : (s < 4) ? (2 + 2 * mid + (s - 2))
       : (((s - 4) < 2 * mid) ? (s - 2) : s);
}

__device__ inline void st_pair(uint32x2* p, uint32x2 v) {
  asm volatile("global_store_dwordx2 %0, %1, off sc0 sc1" :: "v"(p), "v"(v) : "memory");
}

__global__ __launch_bounds__(512, 2) void lstm_persistent(
    const float* __restrict__ x, const float* __restrict__ W_ih,
    const float* __restrict__ W_hh, const float* __restrict__ b_ih,
    const float* __restrict__ b_hh, float* __restrict__ out,
    uint32x2* __restrict__ hbuf)
{
  __shared__ __align__(16) unsigned short v_lds[2][BATCH_G * VSTRIDE];

  const int tid  = threadIdx.x;
  const int gid  = blockIdx.x & 63;   // batch group (16 batches)
  const int mid  = blockIdx.x >> 6;   // member 0..3 (owns gate cols [mid*64, +64))
  const int wv   = tid >> 6;          // wave 0..7
  const int l    = tid & 63;
  const int l15  = l & 15, quad = l >> 4;
  const int rg   = wv;                // row-group 0..7: local cols [8*rg, +8)

  // ---- A-fragments in SLOT order (0,1=x; 2,3=own h; 4..9=remote h) ----
  bf16x8 afrag[2][10];
#pragma unroll
  for (int rt = 0; rt < 2; ++rt) {
    int grow = (l15 & 3) * H_DIM + mid * 64 + rg * 8 + rt * 4 + (l15 >> 2);
    const float* wih_row = W_ih + (long)grow * I_DIM;
    const float* whh_row = W_hh + (long)grow * H_DIM;
#pragma unroll
    for (int s = 0; s < 10; ++s) {
      int kt = slot_kt(s, mid);
      int kbase = kt * 32 + quad * 8;
      ushort8_t a;
#pragma unroll
      for (int e = 0; e < 8; ++e) {
        int k = kbase + e;
        float v = (k < I_DIM) ? wih_row[k] : whh_row[k - I_DIM];
        a[e] = f2bf(v);
      }
      afrag[rt][s] = __builtin_bit_cast(bf16x8, a);
    }
  }

  // ---- bias as acc-init: lane's cell = (col = rg*8+rt*4+quad, batch = l15) ----
  f32x4 bias[2];
#pragma unroll
  for (int rt = 0; rt < 2; ++rt) {
#pragma unroll
    for (int g = 0; g < 4; ++g) {
      int grow = g * H_DIM + mid * 64 + rg * 8 + rt * 4 + quad;
      bias[rt][g] = b_ih[grow] + b_hh[grow];
    }
  }

  const int batch = l15;              // 0..15 within group
  float c_reg[2] = {0.f, 0.f};
  float h_keep[2];

  // ---- x staging: 32 threads per batch row (float2 each) ----
  const int b_stage = tid >> 5;          // 0..15
  const int x_i2    = (tid & 31) * 2;    // 2 floats of x
  const float* xrow = x + ((long)(gid * BATCH_G + b_stage)) * T_STEPS * I_DIM + x_i2;

  // ---- consumer: per-lane remote fragment source. For remote tile kt, lane
  //      needs h-cols [(kt-2)*32 + quad*8, +8) of its batch = pairs
  //      p0..p0+3 (p0 = (kt-2)*16 + quad*4), each 8 B at stride 128 B.
  //      Lanes l15 contiguous -> 128 B coalesced per pair row. ----
  const uint32x2* rbase0 = hbuf + (long)gid * PAIRS * BATCH_G + batch;

  // ---- producer store: pair = mid*32 + rg*4 + rt*2 + (quad>>1), batch = l15
  //      -> lanes l15 contiguous => 128 B runs, full sectors. ----
  uint32x2* st_base = hbuf + ((long)gid * PAIRS + mid * 32 + rg * 4 + (quad >> 1)) * BATCH_G + batch;
  const long buf_stride = (long)NGROUP * PAIRS * BATCH_G;

  // ---- pre-zero own-h region of buffer 1 (t=1 phase-1 reads zeros) ----
  {
    int zr = tid >> 5, zc = (tid & 31) * 2;
    *(unsigned*)&v_lds[1][zr * VSTRIDE + I_DIM + zc] = 0u;
  }

  // ---- x prefetch one step ahead (HBM latency off the critical path) ----
  float2 xv = *(const float2*)xrow;     // row for t=1

  for (int t = 1; t <= T_STEPS; ++t) {
    unsigned short* vbuf = v_lds[t & 1];

    // ---- stage prefetched x_t, then issue the next row's load ----
    {
      ushort2 xb;
      xb.x = f2bf(xv.x); xb.y = f2bf(xv.y);
      *(ushort2*)&vbuf[b_stage * VSTRIDE + x_i2] = xb;
    }
    if (t < T_STEPS) xv = *(const float2*)(xrow + (long)t * I_DIM);

    __syncthreads();   // the ONLY barrier per step

    // ---- phase-1a: x tiles (slots 0,1). LDS row = [x(64) | own-h(64)] ----
    f32x4 acc0 = bias[0], acc1 = bias[1];
    const unsigned short* vb = vbuf + (unsigned)batch * VSTRIDE + quad * 8;
#pragma unroll
    for (int s = 0; s < 2; ++s) {
      bf16x8 bv = __builtin_bit_cast(bf16x8, *(const uint32x4*)(vb + s * 32));
      acc0 = __builtin_amdgcn_mfma_f32_16x16x32_bf16(afrag[0][s], bv, acc0, 0, 0, 0);
      acc1 = __builtin_amdgcn_mfma_f32_16x16x32_bf16(afrag[1][s], bv, acc1, 0, 0, 0);
    }

    // ---- bulk-issue 24 remote pair loads (6 tiles x 4 pairs, no wait) ----
    uint32x2 rr[6][4];
    const uint32x2* rb = rbase0 + ((t - 1) & 1) * buf_stride;
#pragma unroll
    for (int f = 0; f < 6; ++f) {
      int kt = slot_kt(4 + f, mid);
      const uint32x2* pf = rb + ((kt - 2) * 16 + quad * 4) * BATCH_G;
      asm volatile(
          "global_load_dwordx2 %0, %4, off sc0 sc1\n\t"
          "global_load_dwordx2 %1, %4, off offset:128 sc0 sc1\n\t"
          "global_load_dwordx2 %2, %4, off offset:256 sc0 sc1\n\t"
          "global_load_dwordx2 %3, %4, off offset:384 sc0 sc1"
          : "=&v"(rr[f][0]), "=&v"(rr[f][1]), "=&v"(rr[f][2]), "=&v"(rr[f][3])
          : "v"(pf) : "memory");
    }

    // ---- phase-1b: own-h tiles (slots 2,3) — covers the load round trip ----
#pragma unroll
    for (int s = 2; s < 4; ++s) {
      bf16x8 bv = __builtin_bit_cast(bf16x8, *(const uint32x4*)(vb + s * 32));
      acc0 = __builtin_amdgcn_mfma_f32_16x16x32_bf16(afrag[0][s], bv, acc0, 0, 0, 0);
      acc1 = __builtin_amdgcn_mfma_f32_16x16x32_bf16(afrag[1][s], bv, acc1, 0, 0, 0);
    }

    // ---- phase-2: per remote tile, per-lane tag check + bounded retry,
    //      then MFMA. A wave stalls only on ITS OWN data. ----
    const unsigned tag = (unsigned)(t - 1);   // t==1: memset tags==0 match, data==0
#pragma unroll
    for (int f = 0; f < 6; ++f) {
      // make rr[f] appear written by this wait: checks can't be hoisted above it
      asm volatile("s_waitcnt vmcnt(0)"
                   : "+v"(rr[f][0]), "+v"(rr[f][1]), "+v"(rr[f][2]), "+v"(rr[f][3])
                   :: "memory");
      int it = 0;
      while (!((rr[f][0][0] == tag) & (rr[f][1][0] == tag) &
               (rr[f][2][0] == tag) & (rr[f][3][0] == tag))) {
        if (++it > VALVE) break;   // bounded: ~1.2ms worst case, never watchdog
        __builtin_amdgcn_s_sleep(1);
        int kt = slot_kt(4 + f, mid);
        const uint32x2* pf = rb + ((kt - 2) * 16 + quad * 4) * BATCH_G;
        asm volatile(
            "global_load_dwordx2 %0, %4, off sc0 sc1\n\t"
            "global_load_dwordx2 %1, %4, off offset:128 sc0 sc1\n\t"
            "global_load_dwordx2 %2, %4, off offset:256 sc0 sc1\n\t"
            "global_load_dwordx2 %3, %4, off offset:384 sc0 sc1\n\t"
            "s_waitcnt vmcnt(0)"
            : "=&v"(rr[f][0]), "=&v"(rr[f][1]), "=&v"(rr[f][2]), "=&v"(rr[f][3])
            : "v"(pf) : "memory");
      }
      uint32x4 dw;
      dw[0] = rr[f][0][1]; dw[1] = rr[f][1][1];
      dw[2] = rr[f][2][1]; dw[3] = rr[f][3][1];
      bf16x8 bv = __builtin_bit_cast(bf16x8, dw);
      acc0 = __builtin_amdgcn_mfma_f32_16x16x32_bf16(afrag[0][4 + f], bv, acc0, 0, 0, 0);
      acc1 = __builtin_amdgcn_mfma_f32_16x16x32_bf16(afrag[1][4 + f], bv, acc1, 0, 0, 0);
    }

    // ---- cell fully in registers; own-slice to LDS; tagged pair to global.
    //      Producer-critical path: boost wave priority. ----
    __builtin_amdgcn_s_setprio(1);
    unsigned short* next_own = v_lds[(t + 1) & 1] + (unsigned)batch * VSTRIDE + I_DIM;
#pragma unroll
    for (int rt = 0; rt < 2; ++rt) {
      const f32x4 acc = rt ? acc1 : acc0;
      float c = sigf(acc[1]) * c_reg[rt] + sigf(acc[0]) * tanhfast(acc[2]);
      float h = sigf(acc[3]) * tanhfast(c);
      c_reg[rt] = c; h_keep[rt] = h;
      unsigned short hb16 = f2bf(h);
      next_own[rg * 8 + rt * 4 + quad] = hb16;                    // LDS shortcut (own WG)
      unsigned hb = (unsigned)hb16;
      unsigned partner = (unsigned)__shfl_xor((int)hb, 16, 64);   // col^1, same batch
      if (!(quad & 1)) {
        uint32x2 pv;
        pv[0] = (unsigned)t;                  // tag
        pv[1] = hb | (partner << 16);         // (col, col+1)
        st_pair(st_base + rt * 2 * BATCH_G + (t & 1) * buf_stride, pv);  // fire-and-forget
      }
    }
    __builtin_amdgcn_s_setprio(0);
  }

  // ---- outputs: h_T then c_T, fp32 (pre-bf16-rounding values) ----
#pragma unroll
  for (int rt = 0; rt < 2; ++rt) {
    int gcol = mid * 64 + rg * 8 + rt * 4 + quad;
    long o = (long)(gid * BATCH_G + batch) * H_DIM + gcol;
    out[o]            = h_keep[rt];
    out[OUT_HALF + o] = c_reg[rt];
  }
}

extern "C" void kernel_launch(void* const* d_in, const int* in_sizes, int n_in,
                              void* d_out, int out_size, void* d_ws, size_t ws_size,
                              hipStream_t stream) {
  const float* x    = (const float*)d_in[0];
  const float* W_ih = (const float*)d_in[1];
  const float* W_hh = (const float*)d_in[2];
  const float* b_ih = (const float*)d_in[3];
  const float* b_hh = (const float*)d_in[4];
  float* out = (float*)d_out;

  uint32x2* hbuf = (uint32x2*)d_ws;   // 2 buffers x 64 groups x 128 pairs x 16 batch x 8 B = 2 MB

  // Clear tags+data: tag 0 == (t=1)-1 makes step 1 read zeros with no special case.
  hipMemsetAsync(d_ws, 0, 2u * NGROUP * PAIRS * BATCH_G * 8u, stream);
  lstm_persistent<<<dim3(256), dim3(512), 0, stream>>>(x, W_ih, W_hh, b_ih, b_hh, out, hbuf);
}